// Round 3
// baseline (1205.827 us; speedup 1.0000x reference)
//
#include <hip/hip_runtime.h>

#define DD 128

// One wave (64 lanes) per edge: gather feat_src[src], scale by norm,
// atomic-add into agg[dst]; lane 0 accumulates the norm sum per dst node.
// agg aliases the output buffer (zeroed first; finish_kernel later overwrites
// it in place, block-exclusively).
__global__ __launch_bounds__(256) void scatter_kernel(
    const float* __restrict__ feat_src,
    const int* __restrict__ src,
    const int* __restrict__ dst,
    const float* __restrict__ norm,
    float* agg,
    float* ssum,
    int E)
{
    int gw = (int)((blockIdx.x * 256u + threadIdx.x) >> 6);
    int lane = threadIdx.x & 63;
    if (gw >= E) return;
    int si = src[gw];
    int di = dst[gw];
    float nv = norm[gw];
    float2 v = *(const float2*)(feat_src + (size_t)si * DD + lane * 2);
    float* ap = agg + (size_t)di * DD + lane * 2;
    unsafeAtomicAdd(ap,     v.x * nv);
    unsafeAtomicAdd(ap + 1, v.y * nv);
    if (lane == 0) unsafeAtomicAdd(ssum + di, nv);
}

// Per block: 16 rows. h = (feat+agg)@W1 + (agg*feat)@W2 + (1+s)*b1 + s*b2,
// then leaky_relu(0.2) and L2 row-normalize. agg ALIASES out: each block
// stages its 16 rows into LDS (then __syncthreads) before overwriting them.
// Thread layout: c0 = tid&63 (cols c0, c0+64), rg = tid>>6 (rows rg*4..+3).
__global__ __launch_bounds__(256) void finish_kernel(
    const float* __restrict__ feat,
    const float* agg,
    const float* __restrict__ ssum,
    const float* __restrict__ W1,
    const float* __restrict__ b1,
    const float* __restrict__ W2,
    const float* __restrict__ b2,
    float* out,
    int nrows)
{
    __shared__ float xs[16][DD];
    __shared__ float ys[16][DD];
    int row0 = blockIdx.x * 16;
    int tid = threadIdx.x;

    // Stage x = feat+agg, y = feat*agg for 16 rows into LDS (float4 loads).
    for (int i = tid; i < 16 * (DD / 4); i += 256) {
        int r = i >> 5;
        int c4 = (i & 31) * 4;
        int row = row0 + r;
        if (row < nrows) {
            float4 f = *(const float4*)(feat + (size_t)row * DD + c4);
            float4 a = *(const float4*)(agg  + (size_t)row * DD + c4);
            float4 x, y;
            x.x = f.x + a.x; x.y = f.y + a.y; x.z = f.z + a.z; x.w = f.w + a.w;
            y.x = f.x * a.x; y.y = f.y * a.y; y.z = f.z * a.z; y.w = f.w * a.w;
            *(float4*)&xs[r][c4] = x;
            *(float4*)&ys[r][c4] = y;
        }
    }
    __syncthreads();

    int c0 = tid & 63;
    int rg = tid >> 6;
    int c1 = c0 + 64;

    float acc[4][2] = {{0.f,0.f},{0.f,0.f},{0.f,0.f},{0.f,0.f}};
    for (int k = 0; k < DD; k += 4) {
        float w1a[4], w1b[4], w2a[4], w2b[4];
        #pragma unroll
        for (int kk = 0; kk < 4; ++kk) {
            const float* wr1 = W1 + (size_t)(k + kk) * DD;
            const float* wr2 = W2 + (size_t)(k + kk) * DD;
            w1a[kk] = wr1[c0]; w1b[kk] = wr1[c1];
            w2a[kk] = wr2[c0]; w2b[kk] = wr2[c1];
        }
        #pragma unroll
        for (int r = 0; r < 4; ++r) {
            float4 xv = *(const float4*)&xs[rg * 4 + r][k];
            float4 yv = *(const float4*)&ys[rg * 4 + r][k];
            acc[r][0] += xv.x*w1a[0] + xv.y*w1a[1] + xv.z*w1a[2] + xv.w*w1a[3]
                       + yv.x*w2a[0] + yv.y*w2a[1] + yv.z*w2a[2] + yv.w*w2a[3];
            acc[r][1] += xv.x*w1b[0] + xv.y*w1b[1] + xv.z*w1b[2] + xv.w*w1b[3]
                       + yv.x*w2b[0] + yv.y*w2b[1] + yv.z*w2b[2] + yv.w*w2b[3];
        }
    }

    float b1c0 = b1[c0], b1c1 = b1[c1];
    float b2c0 = b2[c0], b2c1 = b2[c1];

    #pragma unroll
    for (int r = 0; r < 4; ++r) {
        int row = row0 + rg * 4 + r;
        if (row < nrows) {
            float s = ssum[row];
            float h0 = acc[r][0] + (1.0f + s) * b1c0 + s * b2c0;
            float h1 = acc[r][1] + (1.0f + s) * b1c1 + s * b2c1;
            h0 = h0 >= 0.f ? h0 : 0.2f * h0;
            h1 = h1 >= 0.f ? h1 : 0.2f * h1;
            float loc = h0 * h0 + h1 * h1;
            #pragma unroll
            for (int m = 32; m >= 1; m >>= 1) loc += __shfl_xor(loc, m, 64);
            float inv = 1.0f / fmaxf(sqrtf(loc), 1e-12f);
            out[(size_t)row * DD + c0] = h0 * inv;
            out[(size_t)row * DD + c1] = h1 * inv;
        }
    }
}

extern "C" void kernel_launch(void* const* d_in, const int* in_sizes, int n_in,
                              void* d_out, int out_size, void* d_ws, size_t ws_size,
                              hipStream_t stream) {
    const float* feat_user = (const float*)d_in[0];
    const float* feat_item = (const float*)d_in[1];
    const float* W1        = (const float*)d_in[2];
    const float* b1        = (const float*)d_in[3];
    const float* W2        = (const float*)d_in[4];
    const float* b2        = (const float*)d_in[5];
    const float* norm_u2i  = (const float*)d_in[6];
    const float* norm_i2u  = (const float*)d_in[7];
    const int* eus = (const int*)d_in[8];
    const int* eud = (const int*)d_in[9];
    const int* eis = (const int*)d_in[10];
    const int* eid = (const int*)d_in[11];

    int NU = in_sizes[0] / DD;
    int NI = in_sizes[1] / DD;
    int E1 = in_sizes[8];
    int E2 = in_sizes[10];
    float* out = (float*)d_out;

    // agg accumulators ALIAS d_out (exactly (NU+NI)*DD floats) — avoids the
    // round-2 bug where 77 MB of "scratch" overran ws_size and corrupted the
    // harness's pristine input copies. Only ssum (600 KB) lives in d_ws.
    float* agg_user = out;                       // NU*DD floats
    float* agg_item = out + (size_t)NU * DD;     // NI*DD floats
    float* s_user   = (float*)d_ws;              // NU floats
    float* s_item   = s_user + NU;               // NI floats

    hipMemsetAsync(out, 0, (size_t)out_size * sizeof(float), stream);
    hipMemsetAsync(d_ws, 0, (size_t)(NU + NI) * sizeof(float), stream);

    // u->i edges accumulate into items; i->u into users.
    {
        int blocks = (int)(((long long)E1 * 64 + 255) / 256);
        scatter_kernel<<<blocks, 256, 0, stream>>>(feat_user, eus, eud, norm_u2i,
                                                   agg_item, s_item, E1);
    }
    {
        int blocks = (int)(((long long)E2 * 64 + 255) / 256);
        scatter_kernel<<<blocks, 256, 0, stream>>>(feat_item, eis, eid, norm_i2u,
                                                   agg_user, s_user, E2);
    }

    finish_kernel<<<(NU + 15) / 16, 256, 0, stream>>>(feat_user, agg_user, s_user,
                                                      W1, b1, W2, b2, out, NU);
    finish_kernel<<<(NI + 15) / 16, 256, 0, stream>>>(feat_item, agg_item, s_item,
                                                      W1, b1, W2, b2,
                                                      out + (size_t)NU * DD, NI);
}

// Round 4
// 834.974 us; speedup vs baseline: 1.4441x; 1.4441x over previous
//
#include <hip/hip_runtime.h>

#define DD 128

// ---------------- CSR-build path (no float atomics) ----------------

// Histogram edge destinations for both directions in one launch.
__global__ __launch_bounds__(256) void count_kernel(
    const int* __restrict__ dst1, int E1, int* deg1,
    const int* __restrict__ dst2, int E2, int* deg2)
{
    int t = blockIdx.x * 256 + threadIdx.x;
    if (t < E1) {
        atomicAdd(deg1 + dst1[t], 1);
    } else if (t - E1 < E2) {
        atomicAdd(deg2 + dst2[t - E1], 1);
    }
}

// Exclusive scan: block 0 -> (deg_i -> row_i), block 1 -> (deg_u -> row_u).
// In place: cur (= deg array) is rewritten to the exclusive prefix (cursor),
// rowptr written separately, rowptr[N] = total.
__global__ __launch_bounds__(1024) void scan_kernel(
    int* cur_i, int* row_i, int NI,
    int* cur_u, int* row_u, int NU)
{
    __shared__ int part[1024];
    int* cur = blockIdx.x == 0 ? cur_i : cur_u;
    int* row = blockIdx.x == 0 ? row_i : row_u;
    int N = blockIdx.x == 0 ? NI : NU;
    int t = threadIdx.x;
    int chunk = (N + 1023) >> 10;
    int base = t * chunk;

    int sum = 0;
    for (int i = 0; i < chunk; ++i) {
        int idx = base + i;
        if (idx < N) sum += cur[idx];
    }
    part[t] = sum;
    __syncthreads();
    // Hillis-Steele inclusive scan over 1024 partials.
    for (int off = 1; off < 1024; off <<= 1) {
        int v = (t >= off) ? part[t - off] : 0;
        __syncthreads();
        part[t] += v;
        __syncthreads();
    }
    int running = part[t] - sum;   // exclusive offset for this chunk
    for (int i = 0; i < chunk; ++i) {
        int idx = base + i;
        if (idx < N) {
            int d = cur[idx];      // read before overwrite (cur aliases deg)
            row[idx] = running;
            cur[idx] = running;    // cursor = start position
            running += d;
        }
    }
    if (t == 1023) row[N] = part[1023];
}

// Scatter edge ids into destination-grouped order (both directions).
__global__ __launch_bounds__(256) void fill_kernel(
    const int* __restrict__ dst1, int E1, int* cur1, int* perm1,
    const int* __restrict__ dst2, int E2, int* cur2, int* perm2)
{
    int t = blockIdx.x * 256 + threadIdx.x;
    if (t < E1) {
        int pos = atomicAdd(cur1 + dst1[t], 1);
        perm1[pos] = t;
    } else if (t - E1 < E2) {
        int e = t - E1;
        int pos = atomicAdd(cur2 + dst2[e], 1);
        perm2[pos] = e;
    }
}

// One wave per destination node; first NI waves = items (dir u2i),
// next NU waves = users (dir i2u). Gathers norm-weighted source rows,
// writes agg (aliases d_out) and ssum. No atomics.
__global__ __launch_bounds__(256) void gather_kernel(
    const int* __restrict__ row_i, const int* __restrict__ perm1,
    const int* __restrict__ src1,  const float* __restrict__ norm1,
    const float* __restrict__ feat_user, float* agg_item, float* ssum_i, int NI,
    const int* __restrict__ row_u, const int* __restrict__ perm2,
    const int* __restrict__ src2,  const float* __restrict__ norm2,
    const float* __restrict__ feat_item, float* agg_user, float* ssum_u, int NU)
{
    int gw = (int)((blockIdx.x * 256u + threadIdx.x) >> 6);
    int lane = threadIdx.x & 63;
    if (gw >= NI + NU) return;

    const int *row, *perm, *src;
    const float *norm, *feat;
    float *agg, *ssum;
    int d;
    if (gw < NI) {
        d = gw;      row = row_i; perm = perm1; src = src1; norm = norm1;
        feat = feat_user; agg = agg_item; ssum = ssum_i;
    } else {
        d = gw - NI; row = row_u; perm = perm2; src = src2; norm = norm2;
        feat = feat_item; agg = agg_user; ssum = ssum_u;
    }

    int beg = row[d], end = row[d + 1];
    float2 acc = {0.f, 0.f};
    float sn = 0.f;
    int j = beg;
    for (; j + 1 < end; j += 2) {           // unroll 2 for load ILP
        int e0 = perm[j], e1 = perm[j + 1];
        int s0 = src[e0], s1 = src[e1];
        float n0 = norm[e0], n1 = norm[e1];
        float2 v0 = *(const float2*)(feat + (size_t)s0 * DD + lane * 2);
        float2 v1 = *(const float2*)(feat + (size_t)s1 * DD + lane * 2);
        acc.x += n0 * v0.x + n1 * v1.x;
        acc.y += n0 * v0.y + n1 * v1.y;
        sn += n0 + n1;
    }
    if (j < end) {
        int e0 = perm[j];
        int s0 = src[e0];
        float n0 = norm[e0];
        float2 v0 = *(const float2*)(feat + (size_t)s0 * DD + lane * 2);
        acc.x += n0 * v0.x;
        acc.y += n0 * v0.y;
        sn += n0;
    }
    *(float2*)(agg + (size_t)d * DD + lane * 2) = acc;
    if (lane == 0) ssum[d] = sn;
}

// ---------------- Fallback: atomic scatter (proven in R3) ----------------

__global__ __launch_bounds__(256) void scatter_kernel(
    const float* __restrict__ feat_src,
    const int* __restrict__ src,
    const int* __restrict__ dst,
    const float* __restrict__ norm,
    float* agg,
    float* ssum,
    int E)
{
    int gw = (int)((blockIdx.x * 256u + threadIdx.x) >> 6);
    int lane = threadIdx.x & 63;
    if (gw >= E) return;
    int si = src[gw];
    int di = dst[gw];
    float nv = norm[gw];
    float2 v = *(const float2*)(feat_src + (size_t)si * DD + lane * 2);
    float* ap = agg + (size_t)di * DD + lane * 2;
    unsafeAtomicAdd(ap,     v.x * nv);
    unsafeAtomicAdd(ap + 1, v.y * nv);
    if (lane == 0) unsafeAtomicAdd(ssum + di, nv);
}

// ---------------- Finish: h = (f+a)@W1 + (f*a)@W2 + bias, lrelu, l2norm ----

// Per block: 16 rows. agg ALIASES out: rows staged to LDS before overwrite.
__global__ __launch_bounds__(256) void finish_kernel(
    const float* __restrict__ feat,
    const float* agg,
    const float* __restrict__ ssum,
    const float* __restrict__ W1,
    const float* __restrict__ b1,
    const float* __restrict__ W2,
    const float* __restrict__ b2,
    float* out,
    int nrows)
{
    __shared__ float xs[16][DD];
    __shared__ float ys[16][DD];
    int row0 = blockIdx.x * 16;
    int tid = threadIdx.x;

    for (int i = tid; i < 16 * (DD / 4); i += 256) {
        int r = i >> 5;
        int c4 = (i & 31) * 4;
        int row = row0 + r;
        if (row < nrows) {
            float4 f = *(const float4*)(feat + (size_t)row * DD + c4);
            float4 a = *(const float4*)(agg  + (size_t)row * DD + c4);
            float4 x, y;
            x.x = f.x + a.x; x.y = f.y + a.y; x.z = f.z + a.z; x.w = f.w + a.w;
            y.x = f.x * a.x; y.y = f.y * a.y; y.z = f.z * a.z; y.w = f.w * a.w;
            *(float4*)&xs[r][c4] = x;
            *(float4*)&ys[r][c4] = y;
        }
    }
    __syncthreads();

    int c0 = tid & 63;
    int rg = tid >> 6;
    int c1 = c0 + 64;

    float acc[4][2] = {{0.f,0.f},{0.f,0.f},{0.f,0.f},{0.f,0.f}};
    for (int k = 0; k < DD; k += 4) {
        float w1a[4], w1b[4], w2a[4], w2b[4];
        #pragma unroll
        for (int kk = 0; kk < 4; ++kk) {
            const float* wr1 = W1 + (size_t)(k + kk) * DD;
            const float* wr2 = W2 + (size_t)(k + kk) * DD;
            w1a[kk] = wr1[c0]; w1b[kk] = wr1[c1];
            w2a[kk] = wr2[c0]; w2b[kk] = wr2[c1];
        }
        #pragma unroll
        for (int r = 0; r < 4; ++r) {
            float4 xv = *(const float4*)&xs[rg * 4 + r][k];
            float4 yv = *(const float4*)&ys[rg * 4 + r][k];
            acc[r][0] += xv.x*w1a[0] + xv.y*w1a[1] + xv.z*w1a[2] + xv.w*w1a[3]
                       + yv.x*w2a[0] + yv.y*w2a[1] + yv.z*w2a[2] + yv.w*w2a[3];
            acc[r][1] += xv.x*w1b[0] + xv.y*w1b[1] + xv.z*w1b[2] + xv.w*w1b[3]
                       + yv.x*w2b[0] + yv.y*w2b[1] + yv.z*w2b[2] + yv.w*w2b[3];
        }
    }

    float b1c0 = b1[c0], b1c1 = b1[c1];
    float b2c0 = b2[c0], b2c1 = b2[c1];

    #pragma unroll
    for (int r = 0; r < 4; ++r) {
        int row = row0 + rg * 4 + r;
        if (row < nrows) {
            float s = ssum[row];
            float h0 = acc[r][0] + (1.0f + s) * b1c0 + s * b2c0;
            float h1 = acc[r][1] + (1.0f + s) * b1c1 + s * b2c1;
            h0 = h0 >= 0.f ? h0 : 0.2f * h0;
            h1 = h1 >= 0.f ? h1 : 0.2f * h1;
            float loc = h0 * h0 + h1 * h1;
            #pragma unroll
            for (int m = 32; m >= 1; m >>= 1) loc += __shfl_xor(loc, m, 64);
            float inv = 1.0f / fmaxf(sqrtf(loc), 1e-12f);
            out[(size_t)row * DD + c0] = h0 * inv;
            out[(size_t)row * DD + c1] = h1 * inv;
        }
    }
}

extern "C" void kernel_launch(void* const* d_in, const int* in_sizes, int n_in,
                              void* d_out, int out_size, void* d_ws, size_t ws_size,
                              hipStream_t stream) {
    const float* feat_user = (const float*)d_in[0];
    const float* feat_item = (const float*)d_in[1];
    const float* W1        = (const float*)d_in[2];
    const float* b1        = (const float*)d_in[3];
    const float* W2        = (const float*)d_in[4];
    const float* b2        = (const float*)d_in[5];
    const float* norm_u2i  = (const float*)d_in[6];
    const float* norm_i2u  = (const float*)d_in[7];
    const int* eus = (const int*)d_in[8];
    const int* eud = (const int*)d_in[9];
    const int* eis = (const int*)d_in[10];
    const int* eid = (const int*)d_in[11];

    int NU = in_sizes[0] / DD;
    int NI = in_sizes[1] / DD;
    int E1 = in_sizes[8];
    int E2 = in_sizes[10];
    float* out = (float*)d_out;

    // agg aliases d_out (exactly (NU+NI)*DD floats).
    float* agg_user = out;
    float* agg_item = out + (size_t)NU * DD;

    size_t need = ((size_t)3 * NU + 3 * NI + E1 + E2 + 2) * sizeof(int);

    if (ws_size >= need) {
        // ---- CSR gather path (no float atomics) ----
        int* cur_i = (int*)d_ws;            // NI   (deg -> cursor, dir u2i)
        int* cur_u = cur_i + NI;            // NU   (deg -> cursor, dir i2u)
        int* row_i = cur_u + NU;            // NI+1
        int* row_u = row_i + NI + 1;        // NU+1
        int* perm1 = row_u + NU + 1;        // E1 (u2i edge ids grouped by item)
        int* perm2 = perm1 + E1;            // E2 (i2u edge ids grouped by user)
        float* ssum_i = (float*)(perm2 + E2);  // NI
        float* ssum_u = ssum_i + NI;           // NU

        hipMemsetAsync(d_ws, 0, (size_t)(NI + NU) * sizeof(int), stream);

        int eb = (int)(((long long)E1 + E2 + 255) / 256);
        count_kernel<<<eb, 256, 0, stream>>>(eud, E1, cur_i, eid, E2, cur_u);
        scan_kernel<<<2, 1024, 0, stream>>>(cur_i, row_i, NI, cur_u, row_u, NU);
        fill_kernel<<<eb, 256, 0, stream>>>(eud, E1, cur_i, perm1,
                                            eid, E2, cur_u, perm2);

        int gb = (int)(((long long)(NI + NU) * 64 + 255) / 256);
        gather_kernel<<<gb, 256, 0, stream>>>(
            row_i, perm1, eus, norm_u2i, feat_user, agg_item, ssum_i, NI,
            row_u, perm2, eis, norm_i2u, feat_item, agg_user, ssum_u, NU);

        finish_kernel<<<(NU + 15) / 16, 256, 0, stream>>>(
            feat_user, agg_user, ssum_u, W1, b1, W2, b2, out, NU);
        finish_kernel<<<(NI + 15) / 16, 256, 0, stream>>>(
            feat_item, agg_item, ssum_i, W1, b1, W2, b2,
            out + (size_t)NU * DD, NI);
    } else {
        // ---- Fallback: R3 atomic path ----
        float* s_user = (float*)d_ws;
        float* s_item = s_user + NU;

        hipMemsetAsync(out, 0, (size_t)out_size * sizeof(float), stream);
        hipMemsetAsync(d_ws, 0, (size_t)(NU + NI) * sizeof(float), stream);

        int b1n = (int)(((long long)E1 * 64 + 255) / 256);
        scatter_kernel<<<b1n, 256, 0, stream>>>(feat_user, eus, eud, norm_u2i,
                                                agg_item, s_item, E1);
        int b2n = (int)(((long long)E2 * 64 + 255) / 256);
        scatter_kernel<<<b2n, 256, 0, stream>>>(feat_item, eis, eid, norm_i2u,
                                                agg_user, s_user, E2);

        finish_kernel<<<(NU + 15) / 16, 256, 0, stream>>>(
            feat_user, agg_user, s_user, W1, b1, W2, b2, out, NU);
        finish_kernel<<<(NI + 15) / 16, 256, 0, stream>>>(
            feat_item, agg_item, s_item, W1, b1, W2, b2,
            out + (size_t)NU * DD, NI);
    }
}